// Round 1
// baseline (10075.489 us; speedup 1.0000x reference)
//
#include <hip/hip_runtime.h>
#include <cmath>

#define B_   64
#define T_   512
#define IN_  256
#define H_   512
#define OUT_ 256
#define M_   (B_*T_)   // 32768 rows for the input-projection GEMMs

typedef __bf16 bf16x4 __attribute__((ext_vector_type(4)));
typedef __bf16 bf16x8 __attribute__((ext_vector_type(8)));
typedef float  f32x4  __attribute__((ext_vector_type(4)));

// Split fp32 into bf16 hi (truncated, exact) + bf16 lo (RN of remainder).
// hi+lo carries ~17 mantissa bits -> split-bf16 MFMA is fp32-grade.
static __device__ __forceinline__ void split_f32(float x, __bf16 &hi, __bf16 &lo) {
    unsigned u  = __float_as_uint(x);
    unsigned hu = u & 0xffff0000u;
    hi = __builtin_bit_cast(__bf16, (unsigned short)(hu >> 16));
    lo = (__bf16)(x - __uint_as_float(hu));
}

// ---------------- weight prep ----------------
__global__ void split_arr(const float* __restrict__ src, __bf16* __restrict__ hi,
                          __bf16* __restrict__ lo, int n) {
    int i = blockIdx.x * 256 + threadIdx.x;
    if (i < n) { __bf16 h, l; split_f32(src[i], h, l); hi[i] = h; lo[i] = l; }
}

__global__ void bias_comb(const float* __restrict__ a, const float* __restrict__ b,
                          float* __restrict__ o, int n) {
    int i = blockIdx.x * 256 + threadIdx.x;
    if (i < n) o[i] = a[i] + b[i];
}

// ---------------- xp GEMM: C[M,512] = A[M,K](f32) @ W[512,K]^T + bias ----------------
// BM=128 BN=64 BK=32, 256 threads (4 waves), wave w owns rows w*32..w*32+31.
// A is split fp32->hi/lo bf16 during LDS staging; W pre-split in global.
#define GBM 128
#define GBN 64
#define GBK 32
#define LDA 40    // LDS row stride in bf16 (32 + 8 pad -> conflict-friendly)

__global__ __launch_bounds__(256) void gemm_xp(
    const float* __restrict__ A, const __bf16* __restrict__ Whi,
    const __bf16* __restrict__ Wlo, const float* __restrict__ bias,
    float* __restrict__ C, int K)
{
    __shared__ __bf16 sAhi[GBM*LDA], sAlo[GBM*LDA], sBhi[GBN*LDA], sBlo[GBN*LDA];
    const int tid = threadIdx.x;
    const int m0 = blockIdx.y * GBM, n0 = blockIdx.x * GBN;
    const int wave = tid >> 6, lane = tid & 63, lm = lane & 15, q = lane >> 4;

    f32x4 acc[2][4];
#pragma unroll
    for (int i = 0; i < 2; ++i)
#pragma unroll
        for (int j = 0; j < 4; ++j) acc[i][j] = (f32x4){0.f,0.f,0.f,0.f};

    for (int k0 = 0; k0 < K; k0 += GBK) {
        __syncthreads();
        // stage A tile 128x32 fp32 -> hi/lo bf16 (1024 float4 chunks / 256 thr)
#pragma unroll
        for (int i = 0; i < 4; ++i) {
            int c = tid + i * 256;
            int row = c >> 3, pos = c & 7;
            float4 v = *(const float4*)(&A[(size_t)(m0+row)*K + k0 + pos*4]);
            __bf16 h0,l0,h1,l1,h2,l2,h3,l3;
            split_f32(v.x,h0,l0); split_f32(v.y,h1,l1);
            split_f32(v.z,h2,l2); split_f32(v.w,h3,l3);
            *(bf16x4*)(&sAhi[row*LDA + pos*4]) = (bf16x4){h0,h1,h2,h3};
            *(bf16x4*)(&sAlo[row*LDA + pos*4]) = (bf16x4){l0,l1,l2,l3};
        }
        // stage W tile 64x32 (hi and lo), 16B per thread per array
        {
            int row = tid >> 2, pos = (tid & 3) * 8;
            *(bf16x8*)(&sBhi[row*LDA + pos]) =
                *(const bf16x8*)(&Whi[(size_t)(n0+row)*K + k0 + pos]);
            *(bf16x8*)(&sBlo[row*LDA + pos]) =
                *(const bf16x8*)(&Wlo[(size_t)(n0+row)*K + k0 + pos]);
        }
        __syncthreads();

        bf16x8 ah[2], al[2], bh[4], bl[4];
#pragma unroll
        for (int mt = 0; mt < 2; ++mt) {
            int r = wave*32 + mt*16 + lm;
            ah[mt] = *(const bf16x8*)(&sAhi[r*LDA + q*8]);
            al[mt] = *(const bf16x8*)(&sAlo[r*LDA + q*8]);
        }
#pragma unroll
        for (int nt = 0; nt < 4; ++nt) {
            int r = nt*16 + lm;
            bh[nt] = *(const bf16x8*)(&sBhi[r*LDA + q*8]);
            bl[nt] = *(const bf16x8*)(&sBlo[r*LDA + q*8]);
        }
#pragma unroll
        for (int mt = 0; mt < 2; ++mt)
#pragma unroll
            for (int nt = 0; nt < 4; ++nt) {
                acc[mt][nt] = __builtin_amdgcn_mfma_f32_16x16x32_bf16(ah[mt], bh[nt], acc[mt][nt], 0,0,0);
                acc[mt][nt] = __builtin_amdgcn_mfma_f32_16x16x32_bf16(ah[mt], bl[nt], acc[mt][nt], 0,0,0);
                acc[mt][nt] = __builtin_amdgcn_mfma_f32_16x16x32_bf16(al[mt], bh[nt], acc[mt][nt], 0,0,0);
            }
    }
    // epilogue: D row=(q*4+r), col=lane&15  [verified C/D layout]
#pragma unroll
    for (int mt = 0; mt < 2; ++mt)
#pragma unroll
        for (int nt = 0; nt < 4; ++nt)
#pragma unroll
            for (int r = 0; r < 4; ++r) {
                int m = m0 + wave*32 + mt*16 + q*4 + r;
                int n = n0 + nt*16 + lm;
                C[(size_t)m*H_ + n] = acc[mt][nt][r] + bias[n];
            }
}

// ---------------- recurrence: 32 blocks x 16 cols, persistent, 1 barrier/step ----------------
#define RG  32
#define RNC 16
#define LDW 520   // 512 + 8 pad (bf16) -> n*260 dwords mod 32 spreads banks

__global__ __launch_bounds__(256) void rnn_rec(
    const float* __restrict__ xp,                       // [B,T,H] fp32
    const __bf16* __restrict__ Whi, const __bf16* __restrict__ Wlo,  // [H,H]
    __bf16* __restrict__ h_hi, __bf16* __restrict__ h_lo,            // [2][B,H], buf0 zeroed
    float* __restrict__ out_seq,                        // [B,T,H] or null
    float* __restrict__ out_last,                       // [B,H] or null
    int* __restrict__ bar)                              // zeroed
{
    __shared__ __bf16 sWhi[RNC*LDW], sWlo[RNC*LDW];
    const int tid = threadIdx.x;
    const int n0 = blockIdx.x * RNC;
    // load this block's W_hh column-slice (16x512 hi+lo) into LDS once
#pragma unroll
    for (int i = 0; i < 4; ++i) {
        int c = tid + i*256;
        int row = c >> 6, pos = (c & 63) * 8;
        *(bf16x8*)(&sWhi[row*LDW + pos]) = *(const bf16x8*)(&Whi[(size_t)(n0+row)*H_ + pos]);
        *(bf16x8*)(&sWlo[row*LDW + pos]) = *(const bf16x8*)(&Wlo[(size_t)(n0+row)*H_ + pos]);
    }
    __syncthreads();

    const int wave = tid >> 6, lane = tid & 63, lm = lane & 15, q = lane >> 4;
    const int m0 = wave * 16;   // 4 waves cover batch 0..63

    for (int t = 0; t < T_; ++t) {
        const __bf16* shi = h_hi + (size_t)(t & 1) * (B_*H_);
        const __bf16* slo = h_lo + (size_t)(t & 1) * (B_*H_);
        f32x4 acc = (f32x4){0.f,0.f,0.f,0.f};
#pragma unroll 4
        for (int kt = 0; kt < 16; ++kt) {
            int ko = kt*32 + q*8;
            bf16x8 ahv = *(const bf16x8*)(&shi[(size_t)(m0+lm)*H_ + ko]);
            bf16x8 alv = *(const bf16x8*)(&slo[(size_t)(m0+lm)*H_ + ko]);
            bf16x8 bhv = *(const bf16x8*)(&sWhi[lm*LDW + ko]);
            bf16x8 blv = *(const bf16x8*)(&sWlo[lm*LDW + ko]);
            acc = __builtin_amdgcn_mfma_f32_16x16x32_bf16(ahv, bhv, acc, 0,0,0);
            acc = __builtin_amdgcn_mfma_f32_16x16x32_bf16(ahv, blv, acc, 0,0,0);
            acc = __builtin_amdgcn_mfma_f32_16x16x32_bf16(alv, bhv, acc, 0,0,0);
        }
        __bf16* dhi = h_hi + (size_t)((t+1) & 1) * (B_*H_);
        __bf16* dlo = h_lo + (size_t)((t+1) & 1) * (B_*H_);
        const int n = n0 + lm;
#pragma unroll
        for (int r = 0; r < 4; ++r) {
            int m = m0 + q*4 + r;
            float v  = xp[((size_t)m*T_ + t)*H_ + n] + acc[r];
            float hv = tanhf(v);
            __bf16 hh, hl; split_f32(hv, hh, hl);
            dhi[(size_t)m*H_ + n] = hh;
            dlo[(size_t)m*H_ + n] = hl;
            if (out_seq)  out_seq[((size_t)m*T_ + t)*H_ + n] = hv;
            if (out_last && t == T_-1) out_last[(size_t)m*H_ + n] = hv;
        }
        // device-scope counting barrier (monotonic target, no reset needed)
        __syncthreads();
        if (tid == 0) {
            __threadfence();
            __hip_atomic_fetch_add(bar, 1, __ATOMIC_RELEASE, __HIP_MEMORY_SCOPE_AGENT);
            int target = RG * (t + 1);
            while (__hip_atomic_load(bar, __ATOMIC_RELAXED, __HIP_MEMORY_SCOPE_AGENT) < target)
                __builtin_amdgcn_s_sleep(1);
            __threadfence();
        }
        __syncthreads();
    }
}

// ---------------- output projection: out[64,256] = hlast @ Wout^T + bout (fp32) ----------------
__global__ __launch_bounds__(256) void out_proj(
    const float* __restrict__ hlast, const float* __restrict__ Wout,
    const float* __restrict__ bout, float* __restrict__ out)
{
    __shared__ float sh[H_];
    int b = blockIdx.x;
    for (int i = threadIdx.x; i < H_; i += 256) sh[i] = hlast[(size_t)b*H_ + i];
    __syncthreads();
    int o = threadIdx.x;
    const float* wr = &Wout[(size_t)o*H_];
    float acc = 0.f;
#pragma unroll 4
    for (int k = 0; k < H_; k += 4) {
        float4 wv = *(const float4*)(&wr[k]);
        acc += wv.x*sh[k] + wv.y*sh[k+1] + wv.z*sh[k+2] + wv.w*sh[k+3];
    }
    out[(size_t)b*OUT_ + o] = bout[o] + acc;
}

extern "C" void kernel_launch(void* const* d_in, const int* in_sizes, int n_in,
                              void* d_out, int out_size, void* d_ws, size_t ws_size,
                              hipStream_t stream)
{
    const float* x    = (const float*)d_in[0];
    const float* Wih0 = (const float*)d_in[1];
    const float* Whh0 = (const float*)d_in[2];
    const float* bih0 = (const float*)d_in[3];
    const float* bhh0 = (const float*)d_in[4];
    const float* Wih1 = (const float*)d_in[5];
    const float* Whh1 = (const float*)d_in[6];
    const float* bih1 = (const float*)d_in[7];
    const float* bhh1 = (const float*)d_in[8];
    const float* Wout = (const float*)d_in[9];
    const float* bout = (const float*)d_in[10];

    char* w = (char*)d_ws;
    size_t off = 0;
    auto alloc = [&](size_t bytes) -> void* {
        void* p = w + off; off = (off + bytes + 255) & ~(size_t)255; return p;
    };
    float*  xp     = (float*) alloc((size_t)M_*H_*4);      // 64 MB, reused for both layers
    float*  out0   = (float*) alloc((size_t)M_*H_*4);      // 64 MB, layer-0 outputs
    __bf16* wih0hi = (__bf16*)alloc((size_t)H_*IN_*2);
    __bf16* wih0lo = (__bf16*)alloc((size_t)H_*IN_*2);
    __bf16* whh0hi = (__bf16*)alloc((size_t)H_*H_*2);
    __bf16* whh0lo = (__bf16*)alloc((size_t)H_*H_*2);
    __bf16* wih1hi = (__bf16*)alloc((size_t)H_*H_*2);
    __bf16* wih1lo = (__bf16*)alloc((size_t)H_*H_*2);
    __bf16* whh1hi = (__bf16*)alloc((size_t)H_*H_*2);
    __bf16* whh1lo = (__bf16*)alloc((size_t)H_*H_*2);
    float*  bias0  = (float*) alloc(H_*4);
    float*  bias1  = (float*) alloc(H_*4);
    size_t zstart = off;                                   // zero-init region start
    __bf16* h0hi   = (__bf16*)alloc((size_t)2*B_*H_*2);
    __bf16* h0lo   = (__bf16*)alloc((size_t)2*B_*H_*2);
    __bf16* h1hi   = (__bf16*)alloc((size_t)2*B_*H_*2);
    __bf16* h1lo   = (__bf16*)alloc((size_t)2*B_*H_*2);
    int*    bars   = (int*)   alloc(256);
    size_t zlen = off - zstart;
    float*  hlast  = (float*) alloc((size_t)B_*H_*4);
    int* bar0 = bars, *bar1 = bars + 32;

    // zero h double-buffers + barrier counters (ws is poisoned before every launch)
    hipMemsetAsync(w + zstart, 0, zlen, stream);

    // weight split + bias combine
    split_arr<<<(H_*IN_+255)/256, 256, 0, stream>>>(Wih0, wih0hi, wih0lo, H_*IN_);
    split_arr<<<(H_*H_ +255)/256, 256, 0, stream>>>(Whh0, whh0hi, whh0lo, H_*H_);
    split_arr<<<(H_*H_ +255)/256, 256, 0, stream>>>(Wih1, wih1hi, wih1lo, H_*H_);
    split_arr<<<(H_*H_ +255)/256, 256, 0, stream>>>(Whh1, whh1hi, whh1lo, H_*H_);
    bias_comb<<<2, 256, 0, stream>>>(bih0, bhh0, bias0, H_);
    bias_comb<<<2, 256, 0, stream>>>(bih1, bhh1, bias1, H_);

    dim3 ggrid(H_/GBN, M_/GBM);  // (8, 256)
    // layer 0
    gemm_xp<<<ggrid, 256, 0, stream>>>(x, wih0hi, wih0lo, bias0, xp, IN_);
    rnn_rec<<<RG, 256, 0, stream>>>(xp, whh0hi, whh0lo, h0hi, h0lo, out0, nullptr, bar0);
    // layer 1
    gemm_xp<<<ggrid, 256, 0, stream>>>(out0, wih1hi, wih1lo, bias1, xp, H_);
    rnn_rec<<<RG, 256, 0, stream>>>(xp, whh1hi, whh1lo, h1hi, h1lo, nullptr, hlast, bar1);
    // output projection
    out_proj<<<B_, 256, 0, stream>>>(hlast, Wout, bout, (float*)d_out);
}